// Round 6
// baseline (249.709 us; speedup 1.0000x reference)
//
#include <hip/hip_runtime.h>

// NormalLoss fused kernel, round 6 submission.
// Same experiment as R4/R5 (aligned float2-per-lane, shuffle taps, predicated
// edge loads); source cosmetically touched so the build/push hash differs —
// R4/R5 failed twice at container level on byte-identical source, and a
// corrupted artifact-cache entry is the remaining non-kernel explanation.

// Problem constants (B,C,H,W fixed by setup_inputs)
#define BB  16
#define HH  384
#define WW  1280
#define ROWS 16       // rows per strip: 24 strips
#define CPW 128       // columns per wave: 64 lanes x 2 (float2, 8B-aligned)
#define NSLOT 64      // accumulator slots, one 64B line each

// R4 theory recap: R0-R3 all pin at ~95us regardless of VMEM instr count
// (19 vs 7 per iter) and offered waves (15 vs 31.5/CU) -> delivered-BW cap
// ~2-2.6 TB/s for small/misaligned 256B wave-chunks (R3 FETCH +30% from line
// splits). Lever: bytes per request + alignment. Each wave owns 128 ALIGNED
// columns (512B aligned chunk per plane-row load); horizontal taps stay in
// register via 2 shuffles; the two boundary columns get their outer tap from
// one 2-active-lane predicated load per plane (neighbor-wave lines, L2-hot).

// Aligned-pair + edge fetch. edge value only meaningful for lane 0 (col x0-1)
// and lane 63 (col x0+2); other lanes (and out-of-range cols) receive 0.
__device__ __forceinline__ void fetch_pair_edge(const float* __restrict__ plane,
                                                int i, int x0, int ej, bool eok,
                                                float& a, float& b, float& e) {
    const float* row = plane + (size_t)i * WW;
    const float2 ab = *reinterpret_cast<const float2*>(row + x0);   // 8B-aligned
    a = ab.x; b = ab.y;
    e = eok ? row[ej] : 0.f;    // one VMEM instr, 2 active lanes per wave
}

// Horizontal taps for this lane's column pair (a,b).
// left-of-a = lane-1's b (lane0: edge), right-of-b = lane+1's a (lane63: edge).
__device__ __forceinline__ void htaps(float a, float b, float e, int lane,
                                      float& Da, float& Db, float& Ta, float& Tb) {
    float l = __shfl_up(b, 1, 64);
    float r = __shfl_down(a, 1, 64);
    if (lane == 0)  l = e;      // cndmask
    if (lane == 63) r = e;      // cndmask
    const float s = a + b;
    Da = b - l;  Db = r - a;
    Ta = l + s;  Tb = s + r;
}

// Per-column finish: cross products, normalize (rsq), |pred-gt| sum over xyz.
__device__ __forceinline__ float normal_absdiff(const float* gx, const float* gy)
{
    float n0p = gx[1] * gy[2] - gx[2] * gy[1];
    float n1p = gx[2] * gy[0] - gx[0] * gy[2];
    float n2p = gx[0] * gy[1] - gx[1] * gy[0];
    float n0g = gx[4] * gy[5] - gx[5] * gy[4];
    float n1g = gx[5] * gy[3] - gx[3] * gy[5];
    float n2g = gx[3] * gy[4] - gx[4] * gy[3];
    float sp = n0p * n0p + n1p * n1p + n2p * n2p;
    float sg = n0g * n0g + n1g * n1g + n2g * n2g;
    // ref: normal/(sqrt(s)+1e-10); rsq rel-err ~2e-6; guard s~0 -> 0
    float ip = (sp > 1e-20f) ? __builtin_amdgcn_rsqf(sp) : 0.f;
    float ig = (sg > 1e-20f) ? __builtin_amdgcn_rsqf(sg) : 0.f;
    return fabsf(n0p * ip - n0g * ig) + fabsf(n1p * ip - n1g * ig)
         + fabsf(n2p * ip - n2g * ig);
}

__global__ __launch_bounds__(64)
void NormalLoss_44478681317469_main(const float* __restrict__ pred,
                                    const float* __restrict__ gt,
                                    const float* __restrict__ mask,
                                    double* __restrict__ acc)
{
    const int lane = threadIdx.x;                 // 0..63
    const int S    = blockIdx.x * CPW;            // wave's aligned col base
    const int x0   = S + 2 * lane;                // my pair's left column
    const int r0   = blockIdx.y * ROWS;           // strip start row
    const int b    = blockIdx.z;

    // Edge-column fetch config: lane0 -> col S-1, lane63 -> col S+128.
    const int  ej  = (lane == 0) ? (x0 - 1) : (x0 + 2);
    const bool eok = ((lane == 0) || (lane == 63)) && ((unsigned)ej < WW);

    const float* pl[6];
#pragma unroll
    for (int c = 0; c < 3; ++c) {
        pl[c]     = pred + (size_t)(b * 3 + c) * HH * WW;
        pl[3 + c] = gt   + (size_t)(b * 3 + c) * HH * WW;
    }
    const float* mpl = mask + (size_t)b * HH * WW;

    // Rolling D (horiz diff) / T (horiz sum) state for rows i-1, i; per column
    // of the pair (suffix a = col x0, b = col x0+1).
    float Dm1a[6], Dm1b[6], D0a[6], D0b[6];
    float Tm1a[6], Tm1b[6], T0a[6], T0b[6];
    // Raw lookahead: row i+1 currently in flight from memory.
    float Ra[6], Rb[6], Re[6];

#pragma unroll
    for (int c = 0; c < 6; ++c) {
        if (r0 > 0) {   // uniform per block
            float a, bb, e; fetch_pair_edge(pl[c], r0 - 1, x0, ej, eok, a, bb, e);
            htaps(a, bb, e, lane, Dm1a[c], Dm1b[c], Tm1a[c], Tm1b[c]);
        } else { Dm1a[c] = 0.f; Dm1b[c] = 0.f; Tm1a[c] = 0.f; Tm1b[c] = 0.f; }
        {
            float a, bb, e; fetch_pair_edge(pl[c], r0, x0, ej, eok, a, bb, e);
            htaps(a, bb, e, lane, D0a[c], D0b[c], T0a[c], T0b[c]);
        }
    }

    // Issue loads for row r0+1 (consumed at top of first iteration).
#pragma unroll
    for (int c = 0; c < 6; ++c)
        fetch_pair_edge(pl[c], r0 + 1, x0, ej, eok, Ra[c], Rb[c], Re[c]);  // <= row 369
    float2 mrow = *reinterpret_cast<const float2*>(mpl + (size_t)r0 * WW + x0);

    float lsum = 0.f, msum = 0.f;

#pragma unroll 2    // rolling loop: rename-by-2 for the rotate copies
    for (int k = 0; k < ROWS; ++k) {
        const int i = r0 + k;

        // Consume lookahead -> D/T for row i+1 via shuffles.
        float Dp1a[6], Dp1b[6], Tp1a[6], Tp1b[6];
#pragma unroll
        for (int c = 0; c < 6; ++c)
            htaps(Ra[c], Rb[c], Re[c], lane, Dp1a[c], Dp1b[c], Tp1a[c], Tp1b[c]);
        const float2 m = mrow;

        // Prefetch row i+2 (+ next mask row) NOW, overlapping the math below.
        if (i + 2 < HH) {   // uniform per block
#pragma unroll
            for (int c = 0; c < 6; ++c)
                fetch_pair_edge(pl[c], i + 2, x0, ej, eok, Ra[c], Rb[c], Re[c]);
        } else {
#pragma unroll
            for (int c = 0; c < 6; ++c) { Ra[c] = 0.f; Rb[c] = 0.f; Re[c] = 0.f; }
        }
        if (k + 1 < ROWS)
            mrow = *reinterpret_cast<const float2*>(mpl + (size_t)(i + 1) * WW + x0);

        // Gradients (global factor 3 dropped; cancels in normalization)
        float gxa[6], gxb[6], gya[6], gyb[6];
#pragma unroll
        for (int c = 0; c < 6; ++c) {
            gxa[c] = Dm1a[c] + D0a[c] + Dp1a[c];
            gxb[c] = Dm1b[c] + D0b[c] + Dp1b[c];
            gya[c] = Tp1a[c] - Tm1a[c];
            gyb[c] = Tp1b[c] - Tm1b[c];
        }

        const float da = normal_absdiff(gxa, gya);
        const float db = normal_absdiff(gxb, gyb);
        lsum += m.x * da + m.y * db;
        msum += m.x + m.y;

        // Rotate rolling state (plain copies; unroll-2 lets compiler rename).
#pragma unroll
        for (int c = 0; c < 6; ++c) {
            Dm1a[c] = D0a[c]; D0a[c] = Dp1a[c];
            Dm1b[c] = D0b[c]; D0b[c] = Dp1b[c];
            Tm1a[c] = T0a[c]; T0a[c] = Tp1a[c];
            Tm1b[c] = T0b[c]; T0b[c] = Tp1b[c];
        }
    }

    // Single-wave block: pure shuffle reduction, one atomic pair per block.
#pragma unroll
    for (int off = 32; off > 0; off >>= 1) {
        lsum += __shfl_down(lsum, off, 64);
        msum += __shfl_down(msum, off, 64);
    }
    if (lane == 0) {
        const int linear = (blockIdx.z * gridDim.y + blockIdx.y) * gridDim.x + blockIdx.x;
        double* slot = acc + (size_t)(linear & (NSLOT - 1)) * 8;  // 64B stride
        atomicAdd(&slot[0], (double)lsum);
        atomicAdd(&slot[1], (double)msum);
    }
}

__global__ void NormalLoss_44478681317469_final(const double* __restrict__ acc,
                                                float* __restrict__ out)
{
    const int t = threadIdx.x;   // 64 threads, one per slot
    double L = acc[(size_t)t * 8 + 0];
    double M = acc[(size_t)t * 8 + 1];
#pragma unroll
    for (int off = 32; off > 0; off >>= 1) {
        L += __shfl_down(L, off, 64);
        M += __shfl_down(M, off, 64);
    }
    if (t == 0) out[0] = (float)(L / M);
}

extern "C" void kernel_launch(void* const* d_in, const int* in_sizes, int n_in,
                              void* d_out, int out_size, void* d_ws, size_t ws_size,
                              hipStream_t stream)
{
    const float* pred = (const float*)d_in[0];
    const float* gt   = (const float*)d_in[1];
    const float* mask = (const float*)d_in[2];
    double* acc = (double*)d_ws;

    // d_ws is poisoned 0xAA before every timed launch — zero the slot array.
    hipMemsetAsync(acc, 0, NSLOT * 8 * sizeof(double), stream);

    dim3 grid(WW / CPW, HH / ROWS, BB);   // 10 x 24 x 16 = 3840 single-wave blocks
    NormalLoss_44478681317469_main<<<grid, dim3(64), 0, stream>>>(pred, gt, mask, acc);
    NormalLoss_44478681317469_final<<<1, 64, 0, stream>>>(acc, (float*)d_out);
}

// Round 7
// 244.047 us; speedup vs baseline: 1.0232x; 1.0232x over previous
//
#include <hip/hip_runtime.h>

// Problem constants (B,C,H,W fixed by setup_inputs)
#define BB  16
#define HH  384
#define WW  1280
#define ROWS 16       // rows per strip: 24 strips
#define CPW 256       // columns per wave: 64 lanes x 4 (float4, 16B-aligned)
#define NSLOT 64      // accumulator slots, one 64B line each

// R7 theory: R0-R6 invariant = ~320 col-rows/us/CU == ~2.45 TB/s demand rate,
// regardless of VMEM count (19/13/7), waves (6-13/CU), FETCH (135-194 MB).
// All prior versions issue 256-512B chunks at 5KB vertical stride from
// desynchronized waves -> effectively random small-request stream. The 6.3
// TB/s ceiling µbench uses 1024B contiguous wave-requests (float4/lane).
// This round: VEC=4 float4 loads — same request shape as the known-good
// ceiling — per-column inner loop to hold VGPR ~160-190.

// float4 chunk + wave-edge fetch. e meaningful only for lane 0 (col x0-1)
// and lane 63 (col x0+4); other lanes / out-of-range get 0.
__device__ __forceinline__ void load_q(const float* __restrict__ plane, int i, int x0,
                                       int ej, bool eok, float4& v, float& e) {
    const float* row = plane + (size_t)i * WW;
    v = *reinterpret_cast<const float4*>(row + x0);   // 16B-aligned
    e = eok ? row[ej] : 0.f;                          // 1 VMEM, 2 active lanes
}

// Horizontal taps for the 4 columns of v. Neighbor cols via 2 shuffles.
__device__ __forceinline__ void taps4(const float4 v, float e, int lane,
                                      float D[4], float T[4]) {
    float l = __shfl_up(v.w, 1, 64);     // col x0-1 (lane0: edge)
    float r = __shfl_down(v.x, 1, 64);   // col x0+4 (lane63: edge)
    if (lane == 0)  l = e;
    if (lane == 63) r = e;
    const float s01 = v.x + v.y, s23 = v.z + v.w;
    D[0] = v.y - l;   D[1] = v.z - v.x;   D[2] = v.w - v.y;   D[3] = r - v.z;
    T[0] = l + s01;   T[1] = s01 + v.z;   T[2] = v.y + s23;   T[3] = s23 + r;
}

// Per-column finish: cross products, normalize (rsq), |pred-gt| sum over xyz.
__device__ __forceinline__ float normal_absdiff(const float* gx, const float* gy)
{
    float n0p = gx[1] * gy[2] - gx[2] * gy[1];
    float n1p = gx[2] * gy[0] - gx[0] * gy[2];
    float n2p = gx[0] * gy[1] - gx[1] * gy[0];
    float n0g = gx[4] * gy[5] - gx[5] * gy[4];
    float n1g = gx[5] * gy[3] - gx[3] * gy[5];
    float n2g = gx[3] * gy[4] - gx[4] * gy[3];
    float sp = n0p * n0p + n1p * n1p + n2p * n2p;
    float sg = n0g * n0g + n1g * n1g + n2g * n2g;
    // ref: normal/(sqrt(s)+1e-10); rsq rel-err ~2e-6; guard s~0 -> 0
    float ip = (sp > 1e-20f) ? __builtin_amdgcn_rsqf(sp) : 0.f;
    float ig = (sg > 1e-20f) ? __builtin_amdgcn_rsqf(sg) : 0.f;
    return fabsf(n0p * ip - n0g * ig) + fabsf(n1p * ip - n1g * ig)
         + fabsf(n2p * ip - n2g * ig);
}

__global__ __launch_bounds__(64)
void NormalLoss_44478681317469_main(const float* __restrict__ pred,
                                    const float* __restrict__ gt,
                                    const float* __restrict__ mask,
                                    double* __restrict__ acc)
{
    const int lane = threadIdx.x;                 // 0..63
    const int S    = blockIdx.x * CPW;            // wave's aligned col base
    const int x0   = S + 4 * lane;                // my quad's left column
    const int r0   = blockIdx.y * ROWS;           // strip start row
    const int b    = blockIdx.z;

    // Wave-edge fetch: lane0 -> col S-1, lane63 -> col S+256.
    const int  ej  = (lane == 0) ? (x0 - 1) : (x0 + 4);
    const bool eok = ((lane == 0) || (lane == 63)) && ((unsigned)ej < WW);

    const float* pl[6];
#pragma unroll
    for (int c = 0; c < 3; ++c) {
        pl[c]     = pred + (size_t)(b * 3 + c) * HH * WW;
        pl[3 + c] = gt   + (size_t)(b * 3 + c) * HH * WW;
    }
    const float* mpl = mask + (size_t)b * HH * WW;

    // Rolling D (horiz diff) / T (horiz sum) state for rows i-1, i;
    // [plane][column-of-quad], all statically indexed (unrolled loops).
    float Dm1[6][4], D0[6][4], Tm1[6][4], T0[6][4];
    // Raw lookahead: row i+1 currently in flight from memory.
    float4 Rv[6]; float Re[6];

#pragma unroll
    for (int c = 0; c < 6; ++c) {
        if (r0 > 0) {   // uniform per block
            float4 v; float e; load_q(pl[c], r0 - 1, x0, ej, eok, v, e);
            taps4(v, e, lane, Dm1[c], Tm1[c]);
        } else {
#pragma unroll
            for (int q = 0; q < 4; ++q) { Dm1[c][q] = 0.f; Tm1[c][q] = 0.f; }
        }
        {
            float4 v; float e; load_q(pl[c], r0, x0, ej, eok, v, e);
            taps4(v, e, lane, D0[c], T0[c]);
        }
    }

    // Issue loads for row r0+1 (consumed at top of first iteration).
#pragma unroll
    for (int c = 0; c < 6; ++c)
        load_q(pl[c], r0 + 1, x0, ej, eok, Rv[c], Re[c]);   // r0+1 <= 369 < HH
    float4 mrow = *reinterpret_cast<const float4*>(mpl + (size_t)r0 * WW + x0);

    float lsum = 0.f, msum = 0.f;

    for (int k = 0; k < ROWS; ++k) {
        const int i = r0 + k;

        // Neighbor cols of the in-flight row (2 shuffles per plane).
        float lR[6], rR[6];
#pragma unroll
        for (int c = 0; c < 6; ++c) {
            float l = __shfl_up(Rv[c].w, 1, 64);
            float r = __shfl_down(Rv[c].x, 1, 64);
            if (lane == 0)  l = Re[c];
            if (lane == 63) r = Re[c];
            lR[c] = l; rR[c] = r;
        }
        const float4 m = mrow;

        // Per column: gradients across planes -> cross -> normalize -> |diff|.
        // Rotation folded in (state for (c,q) is dead after gx/gy capture).
#pragma unroll
        for (int q = 0; q < 4; ++q) {
            float gx[6], gy[6];
#pragma unroll
            for (int c = 0; c < 6; ++c) {
                const float4 R = Rv[c];
                float Dp1, Tp1;
                if (q == 0)      { Dp1 = R.y - lR[c];  Tp1 = lR[c] + R.x + R.y; }
                else if (q == 1) { Dp1 = R.z - R.x;    Tp1 = R.x + R.y + R.z; }
                else if (q == 2) { Dp1 = R.w - R.y;    Tp1 = R.y + R.z + R.w; }
                else             { Dp1 = rR[c] - R.z;  Tp1 = R.z + R.w + rR[c]; }
                gx[c] = Dm1[c][q] + D0[c][q] + Dp1;   // factor 3 dropped (cancels)
                gy[c] = Tp1 - Tm1[c][q];
                Dm1[c][q] = D0[c][q]; D0[c][q] = Dp1;
                Tm1[c][q] = T0[c][q]; T0[c][q] = Tp1;
            }
            const float mq = (q == 0) ? m.x : (q == 1) ? m.y : (q == 2) ? m.z : m.w;
            lsum += mq * normal_absdiff(gx, gy);
            msum += mq;
        }

        // Prefetch row i+2 (+ next mask row) for the next iteration.
        if (i + 2 < HH) {   // uniform per block
#pragma unroll
            for (int c = 0; c < 6; ++c) load_q(pl[c], i + 2, x0, ej, eok, Rv[c], Re[c]);
        } else {
#pragma unroll
            for (int c = 0; c < 6; ++c) { Rv[c] = make_float4(0.f, 0.f, 0.f, 0.f); Re[c] = 0.f; }
        }
        if (k + 1 < ROWS)
            mrow = *reinterpret_cast<const float4*>(mpl + (size_t)(i + 1) * WW + x0);
    }

    // Single-wave block: pure shuffle reduction, one atomic pair per block.
#pragma unroll
    for (int off = 32; off > 0; off >>= 1) {
        lsum += __shfl_down(lsum, off, 64);
        msum += __shfl_down(msum, off, 64);
    }
    if (lane == 0) {
        const int linear = (blockIdx.z * gridDim.y + blockIdx.y) * gridDim.x + blockIdx.x;
        double* slot = acc + (size_t)(linear & (NSLOT - 1)) * 8;  // 64B stride
        atomicAdd(&slot[0], (double)lsum);
        atomicAdd(&slot[1], (double)msum);
    }
}

__global__ void NormalLoss_44478681317469_final(const double* __restrict__ acc,
                                                float* __restrict__ out)
{
    const int t = threadIdx.x;   // 64 threads, one per slot
    double L = acc[(size_t)t * 8 + 0];
    double M = acc[(size_t)t * 8 + 1];
#pragma unroll
    for (int off = 32; off > 0; off >>= 1) {
        L += __shfl_down(L, off, 64);
        M += __shfl_down(M, off, 64);
    }
    if (t == 0) out[0] = (float)(L / M);
}

extern "C" void kernel_launch(void* const* d_in, const int* in_sizes, int n_in,
                              void* d_out, int out_size, void* d_ws, size_t ws_size,
                              hipStream_t stream)
{
    const float* pred = (const float*)d_in[0];
    const float* gt   = (const float*)d_in[1];
    const float* mask = (const float*)d_in[2];
    double* acc = (double*)d_ws;

    // d_ws is poisoned 0xAA before every timed launch — zero the slot array.
    hipMemsetAsync(acc, 0, NSLOT * 8 * sizeof(double), stream);

    dim3 grid(WW / CPW, HH / ROWS, BB);   // 5 x 24 x 16 = 1920 single-wave blocks
    NormalLoss_44478681317469_main<<<grid, dim3(64), 0, stream>>>(pred, gt, mask, acc);
    NormalLoss_44478681317469_final<<<1, 64, 0, stream>>>(acc, (float*)d_out);
}